// Round 4
// baseline (218.017 us; speedup 1.0000x reference)
//
#include <hip/hip_runtime.h>
#include <limits.h>

// Exploits: batch[] is SORTED -> graph membership is an interval lookup, no gather.
// bnd[17] (lower bounds per graph id) lives in ws; edge kernel caches it in LDS.
// Only same-graph edges (~6.6%) need key-table gathers; other lanes clamp their
// gather index to 0, collapsing to a broadcast line (TCP coalesces same-line).
// ushort key: (batch<<10) | pi ; valid keys have low 10 bits != 0; sentinel 0.
//
// R3 established: t_edge = max(compute, 68ns*nblocks) where the second term was
// the 2-atomic/block chain to one hot line (now removed via per-block partials).
// R4: with contention gone, raise parallelism: exact grid (3125 blocks, one
// 16-edge group per thread, perfectly balanced), launch_bounds(256,4) keeps
// VGPR=44 (R1's spill was the ,8 clamp to 32 VGPR, not the grid size).
// Node kernel vectorized to 8 nodes/thread (int4 loads, 16B packed key store).

typedef int   iv4 __attribute__((ext_vector_type(4)));
typedef float fv4 __attribute__((ext_vector_type(4)));

#define MAX_PART 4096

// focal contribution for one logit x with binary target t (0/1).
// t=1: 0.25 * softplus(-x) * sigmoid(-x)^2 ; t=0: 0.75 * softplus(x) * sigmoid(x)^2
__device__ __forceinline__ float focal_term(float x, int t) {
    float y = t ? -x : x;
    float e = __expf(-fabsf(y));
    float ce = fmaxf(y, 0.f) + __logf(1.f + e);  // softplus(y) == BCE-with-logits
    float inv = __builtin_amdgcn_rcpf(1.f + e);
    float sg = (y >= 0.f) ? inv : e * inv;       // sigmoid(y) == (1 - p_t)
    float w = t ? 0.25f : 0.75f;                 // alpha_t
    return w * ce * sg * sg;                     // gamma = 2
}

__device__ __forceinline__ float acc_term(float x, int t) {
    return ((x > 0.f) == (t != 0)) ? 1.f : 0.f;
}

// Block-reduce two floats; emit either a per-block partial (part != nullptr,
// contention-free) or atomics to acc (fallback only).
__device__ __forceinline__ void block_reduce_out(float v0, float v1,
                                                 float* a0, float* a1,
                                                 float2* part) {
#pragma unroll
    for (int off = 32; off > 0; off >>= 1) {
        v0 += __shfl_down(v0, off, 64);
        v1 += __shfl_down(v1, off, 64);
    }
    __shared__ float s0[8], s1[8];
    int wave = threadIdx.x >> 6;
    int lane = threadIdx.x & 63;
    if (lane == 0) { s0[wave] = v0; s1[wave] = v1; }
    __syncthreads();
    if (threadIdx.x == 0) {
        int nw = blockDim.x >> 6;
        float t0 = 0.f, t1 = 0.f;
        for (int w = 0; w < nw; ++w) { t0 += s0[w]; t1 += s1[w]; }
        if (part) {
            part[blockIdx.x] = make_float2(t0, t1);
        } else {
            atomicAdd(a0, t0);
            atomicAdd(a1, t1);
        }
    }
}

// Kernel A: node loss/acc + ushort key table + graph boundary table bnd[17].
// bnd[k] = first node index with batch >= k (batch sorted). Covers k=0..16
// including empty graphs. 8 nodes/thread, vectorized loads + packed key store.
__global__ void node_key_kernel(const float* __restrict__ nl,
                                const int* __restrict__ batch,
                                const int* __restrict__ pi,
                                int N, unsigned short* __restrict__ key,
                                int* __restrict__ bnd,
                                float* __restrict__ acc,
                                float2* __restrict__ part) {
    int tid = blockIdx.x * blockDim.x + threadIdx.x;
    int nthreads = gridDim.x * blockDim.x;
    int C = N >> 3;  // full 8-chunks
    float ls = 0.f, ac = 0.f;
    const iv4* pi4 = reinterpret_cast<const iv4*>(pi);
    const iv4* b4  = reinterpret_cast<const iv4*>(batch);
    const fv4* nl4 = reinterpret_cast<const fv4*>(nl);

    for (int c = tid; c < C; c += nthreads) {
        int base = c << 3;
        iv4 p0 = pi4[(c << 1) + 0], p1 = pi4[(c << 1) + 1];
        iv4 b0 = b4[(c << 1) + 0],  b1 = b4[(c << 1) + 1];
        fv4 x0 = nl4[(c << 1) + 0], x1 = nl4[(c << 1) + 1];
        int pv[8] = {p0.x, p0.y, p0.z, p0.w, p1.x, p1.y, p1.z, p1.w};
        int bv[8] = {b0.x, b0.y, b0.z, b0.w, b1.x, b1.y, b1.z, b1.w};
        float xv[8] = {x0.x, x0.y, x0.z, x0.w, x1.x, x1.y, x1.z, x1.w};
        int bp = (base > 0) ? batch[base - 1] : -1;  // -1 makes i==0 write bnd[0..b]
        unsigned int kv[8];
#pragma unroll
        for (int j = 0; j < 8; ++j) {
            int p = pv[j];
            int t = (p != 0) ? 1 : 0;
            int b = bv[j];
            kv[j] = t ? (unsigned int)((b << 10) | p) : 0u;
            if (bp != b) {
                for (int k = bp + 1; k <= b; ++k) bnd[k] = base + j;
            }
            bp = b;
            ls += focal_term(xv[j], t);
            ac += acc_term(xv[j], t);
        }
        if (base + 8 == N) {
            for (int k = bv[7] + 1; k <= 16; ++k) bnd[k] = N;
        }
        iv4 kp;
        kp.x = (int)(kv[0] | (kv[1] << 16));
        kp.y = (int)(kv[2] | (kv[3] << 16));
        kp.z = (int)(kv[4] | (kv[5] << 16));
        kp.w = (int)(kv[6] | (kv[7] << 16));
        reinterpret_cast<iv4*>(key)[c] = kp;
    }
    // tail (N % 8), scalar by global thread 0
    if (tid == 0) {
        for (int i = C << 3; i < N; ++i) {
            int p = pi[i];
            int t = (p != 0) ? 1 : 0;
            int b = batch[i];
            key[i] = t ? (unsigned short)((b << 10) | p) : (unsigned short)0;
            if (i == 0) {
                for (int k = 0; k <= b; ++k) bnd[k] = 0;
            } else {
                int bp = batch[i - 1];
                for (int k = bp + 1; k <= b; ++k) bnd[k] = i;
            }
            if (i == N - 1) {
                for (int k = b + 1; k <= 16; ++k) bnd[k] = N;
            }
            float x = nl[i];
            ls += focal_term(x, t);
            ac += acc_term(x, t);
        }
    }
    block_reduce_out(ls, ac, acc + 2, acc + 3, part);
}

// Kernel B: 16 edges/thread, exact grid (one group per thread when
// grid*256 == G16). Same-graph test via interval lookup (no gather);
// key gathers only effectively needed for ~6.6% of lanes (others clamp to
// index 0 -> broadcast line).
__global__ void __launch_bounds__(256, 4)
edge_kernel_key(const float* __restrict__ el,
                const int* __restrict__ src,
                const int* __restrict__ dst,
                const unsigned short* __restrict__ key,
                const int* __restrict__ bnd_g,
                int E, float gscale, float* __restrict__ acc,
                float2* __restrict__ part) {
    __shared__ int bnd[17];
    if (threadIdx.x < 17) bnd[threadIdx.x] = bnd_g[threadIdx.x];
    __syncthreads();

    const int G16 = E >> 4;
    int tid = blockIdx.x * blockDim.x + threadIdx.x;
    int stride = gridDim.x * blockDim.x;
    float ls = 0.f, ac = 0.f;
    const iv4* src4 = reinterpret_cast<const iv4*>(src);
    const iv4* dst4 = reinterpret_cast<const iv4*>(dst);
    const fv4* el4  = reinterpret_cast<const fv4*>(el);

    for (int g = tid; g < G16; g += stride) {
        int base = g << 2;
        int si[16], di[16];
#pragma unroll
        for (int j = 0; j < 4; ++j) {
            iv4 s = __builtin_nontemporal_load(src4 + base + j);
            iv4 d = __builtin_nontemporal_load(dst4 + base + j);
            si[j * 4 + 0] = s.x; si[j * 4 + 1] = s.y;
            si[j * 4 + 2] = s.z; si[j * 4 + 3] = s.w;
            di[j * 4 + 0] = d.x; di[j * 4 + 1] = d.y;
            di[j * 4 + 2] = d.z; di[j * 4 + 3] = d.w;
        }
        // same-graph mask via interval lookup; clamp gather indices for
        // non-same lanes to node 0 (broadcast line, TCP-cheap)
        unsigned int sameMask = 0;
#pragma unroll
        for (int i = 0; i < 16; ++i) {
            int s = si[i], d = di[i];
            int gg = (int)((float)s * gscale);
            gg = gg < 0 ? 0 : (gg > 15 ? 15 : gg);
            int lo = bnd[gg], hi = bnd[gg + 1];
            while (s < lo) { --gg; hi = lo; lo = bnd[gg]; }
            while (s >= hi) { ++gg; lo = hi; hi = bnd[gg + 1]; }
            int same = (d >= lo) & (d < hi);
            sameMask |= (unsigned int)same << i;
            si[i] = same ? s : 0;
            di[i] = same ? d : 0;
        }
        unsigned short ks[16], kd[16];
#pragma unroll
        for (int i = 0; i < 16; ++i) ks[i] = key[si[i]];
#pragma unroll
        for (int i = 0; i < 16; ++i) kd[i] = key[di[i]];
        float xv[16];
#pragma unroll
        for (int j = 0; j < 4; ++j) {
            fv4 x = __builtin_nontemporal_load(el4 + base + j);
            xv[j * 4 + 0] = x.x; xv[j * 4 + 1] = x.y;
            xv[j * 4 + 2] = x.z; xv[j * 4 + 3] = x.w;
        }
#pragma unroll
        for (int i = 0; i < 16; ++i) {
            int t = (int)((sameMask >> i) & 1u) & (ks[i] == kd[i]) & (ks[i] != 0);
            ls += focal_term(xv[i], t);
            ac += acc_term(xv[i], t);
        }
    }
    // tail (E % 16), by global thread 0 (empty for E=12.8M)
    if (tid == 0) {
        for (int i = (G16 << 4); i < E; ++i) {
            int s = src[i], d = dst[i];
            int gg = (int)((float)s * gscale);
            gg = gg < 0 ? 0 : (gg > 15 ? 15 : gg);
            int lo = bnd[gg], hi = bnd[gg + 1];
            while (s < lo) { --gg; hi = lo; lo = bnd[gg]; }
            while (s >= hi) { ++gg; lo = hi; hi = bnd[gg + 1]; }
            int same = (d >= lo) & (d < hi);
            unsigned short ks = key[same ? s : 0], kd = key[same ? d : 0];
            int t = same & (ks == kd) & (ks != 0);
            float x = el[i];
            ls += focal_term(x, t);
            ac += acc_term(x, t);
        }
    }
    block_reduce_out(ls, ac, acc + 0, acc + 1, part);
}

// Fallback (ws too small for key table): 4 gathers per edge, atomic reduce
__global__ void edge_kernel_direct(const float* __restrict__ el,
                                   const int* __restrict__ src,
                                   const int* __restrict__ dst,
                                   const int* __restrict__ batch,
                                   const int* __restrict__ pi,
                                   int E, float* __restrict__ acc) {
    int G = E >> 2;
    int stride = gridDim.x * blockDim.x;
    int tid = blockIdx.x * blockDim.x + threadIdx.x;
    float ls = 0.f, ac = 0.f;
    for (int g = tid; g < G; g += stride) {
        float4 x = reinterpret_cast<const float4*>(el)[g];
        int4 s = reinterpret_cast<const int4*>(src)[g];
        int4 d = reinterpret_cast<const int4*>(dst)[g];
        int is[4] = {s.x, s.y, s.z, s.w};
        int id[4] = {d.x, d.y, d.z, d.w};
        float xs[4] = {x.x, x.y, x.z, x.w};
#pragma unroll
        for (int j = 0; j < 4; ++j) {
            int ps = pi[is[j]], pd = pi[id[j]];
            int t = (ps == pd) & (batch[is[j]] == batch[id[j]]) & (ps != 0);
            ls += focal_term(xs[j], t);
            ac += acc_term(xs[j], t);
        }
    }
    if (tid == 0) {
        for (int i = (G << 2); i < E; ++i) {
            int ps = pi[src[i]], pd = pi[dst[i]];
            int t = (ps == pd) & (batch[src[i]] == batch[dst[i]]) & (ps != 0);
            float x = el[i];
            ls += focal_term(x, t);
            ac += acc_term(x, t);
        }
    }
    block_reduce_out(ls, ac, acc + 0, acc + 1, nullptr);
}

// Kernel C: finalize. use_part: sum per-block partials (contention-free path);
// else read the 4 atomic accumulators. Emits 5 scalars.
__global__ void finalize_kernel(const float* __restrict__ acc,
                                const float2* __restrict__ epart, int ne,
                                const float2* __restrict__ npart, int nn,
                                int use_part,
                                float* __restrict__ out, int E, int N) {
    float el = 0.f, ea = 0.f, nl = 0.f, na = 0.f;
    if (use_part) {
        for (int i = threadIdx.x; i < ne; i += 256) {
            float2 p = epart[i];
            el += p.x; ea += p.y;
        }
        for (int i = threadIdx.x; i < nn; i += 256) {
            float2 p = npart[i];
            nl += p.x; na += p.y;
        }
#pragma unroll
        for (int off = 32; off > 0; off >>= 1) {
            el += __shfl_down(el, off, 64);
            ea += __shfl_down(ea, off, 64);
            nl += __shfl_down(nl, off, 64);
            na += __shfl_down(na, off, 64);
        }
        __shared__ float s[4][4];
        int wave = threadIdx.x >> 6;
        int lane = threadIdx.x & 63;
        if (lane == 0) {
            s[wave][0] = el; s[wave][1] = ea;
            s[wave][2] = nl; s[wave][3] = na;
        }
        __syncthreads();
        if (threadIdx.x == 0) {
            el = 0.f; ea = 0.f; nl = 0.f; na = 0.f;
            for (int w = 0; w < 4; ++w) {
                el += s[w][0]; ea += s[w][1];
                nl += s[w][2]; na += s[w][3];
            }
            float invE = 1.f / (float)E;
            float invN = 1.f / (float)N;
            float elm = el * invE, eam = ea * invE;
            float nlm = nl * invN, nam = na * invN;
            out[0] = elm + nlm;
            out[1] = elm;
            out[2] = nlm;
            out[3] = eam;
            out[4] = nam;
        }
    } else if (threadIdx.x == 0) {
        float invE = 1.f / (float)E;
        float invN = 1.f / (float)N;
        float elm = acc[0] * invE;
        float eam = acc[1] * invE;
        float nlm = acc[2] * invN;
        float nam = acc[3] * invN;
        out[0] = elm + nlm;
        out[1] = elm;
        out[2] = nlm;
        out[3] = eam;
        out[4] = nam;
    }
}

extern "C" void kernel_launch(void* const* d_in, const int* in_sizes, int n_in,
                              void* d_out, int out_size, void* d_ws, size_t ws_size,
                              hipStream_t stream) {
    const float* edge_logits = (const float*)d_in[0];
    const float* node_logits = (const float*)d_in[1];
    const int*   batch       = (const int*)d_in[2];
    const int*   pinst       = (const int*)d_in[3];
    const int*   eidx        = (const int*)d_in[4];
    const int E = in_sizes[0];
    const int N = in_sizes[1];
    const int* src = eidx;
    const int* dst = eidx + E;
    float* out = (float*)d_out;

    // ws layout:
    //   [0..15]      4 float accumulators (atomic fallback only)
    //   [64..131]    bnd[17] ints
    //   [256 ..)     ushort key[N]
    //   key_end_pad  float2 epart[MAX_PART], float2 npart[MAX_PART]
    float* acc = (float*)d_ws;
    int*   bnd = (int*)((char*)d_ws + 64);
    unsigned short* key = (unsigned short*)((char*)d_ws + 256);
    size_t key_end = 256 + (size_t)N * sizeof(unsigned short);
    size_t part_off = (key_end + 255) & ~(size_t)255;
    float2* epart = (float2*)((char*)d_ws + part_off);
    float2* npart = epart + MAX_PART;
    size_t need_full = part_off + 2 * MAX_PART * sizeof(float2);

    const bool use_key  = (ws_size >= key_end);
    const bool use_part = (ws_size >= need_full);

    const int block = 256;
    int C = N >> 3;
    int node_grid = (C + block - 1) / block;
    if (node_grid < 1) node_grid = 1;
    if (node_grid > MAX_PART) node_grid = MAX_PART;  // grid-stride covers rest

    if (!use_part) {
        // atomic fallback needs zeroed accumulators
        (void)hipMemsetAsync(d_ws, 0, 16, stream);
    }

    node_key_kernel<<<node_grid, block, 0, stream>>>(
        node_logits, batch, pinst, N, key, bnd, acc,
        use_part ? npart : nullptr);

    // exact grid: one 16-edge group per thread (3125 blocks @ E=12.8M);
    // contention-free partials make block count cost-free (R3 model).
    int G16 = E >> 4;
    int edge_grid = (G16 + block - 1) / block;
    if (edge_grid < 1) edge_grid = 1;
    if (edge_grid > MAX_PART) edge_grid = MAX_PART;  // grid-stride covers rest

    if (use_key) {
        float gscale = 16.0f / (float)N;
        edge_kernel_key<<<edge_grid, block, 0, stream>>>(
            edge_logits, src, dst, key, bnd, E, gscale, acc,
            use_part ? epart : nullptr);
    } else {
        int G = E >> 2;
        int eg = (G + block - 1) / block;
        if (eg > 65535 * 4) eg = 65535 * 4;
        if (eg < 1) eg = 1;
        edge_kernel_direct<<<eg, block, 0, stream>>>(edge_logits, src, dst,
                                                     batch, pinst, E, acc);
    }

    finalize_kernel<<<1, 256, 0, stream>>>(acc, epart, edge_grid,
                                           npart, node_grid,
                                           (use_key && use_part) ? 1 : 0,
                                           out, E, N);
}